// Round 3
// baseline (70.002 us; speedup 1.0000x reference)
//
#include <hip/hip_runtime.h>

// Problem constants: B=8, N=1024, F=128, H=4, K=32, TAU=1

// ---------------------------------------------------------------------------
// Phase 1: S[bn][k] for all 8192 points.
// 512 blocks x 512 threads; thread t = (hk = t&127, q = t>>7) holds 32 key
// features (8 float4 = 32 VGPRs, asm-pinned) in registers.
// Each block: 16 points as 4 batches of 4. Per batch:
//   distance quarter-sums in regs -> LDS -> full reduce (Student-t +
//   per-head normalize; 512 thr = 4 p x 128 hk) -> LDS -> conv-combine +
//   softmax (128 thr = 4 p x 32 k). 2 barriers + 1 trailing per batch.
// ---------------------------------------------------------------------------
#define P1_BATCH 4
#define P1_NBATCH 4
#define P1_PPB (P1_BATCH * P1_NBATCH)

__global__ __launch_bounds__(512, 4) void mempool_phase1(
    const float* __restrict__ x, const float* __restrict__ keys,
    const float* __restrict__ conv_w, float* __restrict__ S_out) {
  const int t = threadIdx.x;
  const int hk = t & 127;
  const int q = t >> 7;  // quarter 0..3
  const float cw = conv_w[hk >> 5];

  // 32 key features, register-resident and pinned.
  const float4* kq = reinterpret_cast<const float4*>(keys) + hk * 32 + q * 8;
  float4 key[8];
#pragma unroll
  for (int j = 0; j < 8; ++j) key[j] = kq[j];
#pragma unroll
  for (int j = 0; j < 8; ++j)
    asm volatile("" : "+v"(key[j].x), "+v"(key[j].y), "+v"(key[j].z),
                      "+v"(key[j].w));

  __shared__ float accs[P1_BATCH][4][128];  // 8 KB
  __shared__ float cwsn[P1_BATCH][4][32];   // 2 KB

  const int base = blockIdx.x * P1_PPB;
  for (int nb = 0; nb < P1_NBATCH; ++nb) {
    const int b0 = base + nb * P1_BATCH;
    // x float4 base for this thread's quarter; address is wave-uniform.
    const float4* x4 = reinterpret_cast<const float4*>(x) + (size_t)b0 * 32 + q * 8;

    float acc[P1_BATCH] = {0.f, 0.f, 0.f, 0.f};
#pragma unroll 4
    for (int j = 0; j < 8; ++j) {
      const float4 kv = key[j];
#pragma unroll
      for (int p = 0; p < P1_BATCH; ++p) {
        const float4 xv = x4[p * 32 + j];
        acc[p] += fabsf(kv.x - xv.x) + fabsf(kv.y - xv.y) +
                  fabsf(kv.z - xv.z) + fabsf(kv.w - xv.w);
      }
    }

#pragma unroll
    for (int p = 0; p < P1_BATCH; ++p) accs[p][q][hk] = acc[p];
    __syncthreads();

    {  // reduce: thread handles (p = q, hk); 32-lane groups share (p, h)
      const int p = q;
      const float d =
          accs[p][0][hk] + accs[p][1][hk] + accs[p][2][hk] + accs[p][3][hk];
      const float tv = __builtin_amdgcn_rcpf(1.f + d * d);  // Student-t, tau=1
      float hs = tv;
#pragma unroll
      for (int m = 1; m < 32; m <<= 1) hs += __shfl_xor(hs, m);
      cwsn[p][hk >> 5][hk & 31] = cw * tv * __builtin_amdgcn_rcpf(hs);
    }
    __syncthreads();

    if (t < 128) {  // conv-combine + softmax: (p = t>>5, k = t&31)
      const int p = t >> 5;
      const int k = t & 31;
      float sc = cwsn[p][0][k] + cwsn[p][1][k] + cwsn[p][2][k] + cwsn[p][3][k];
      float mx = sc;
#pragma unroll
      for (int m = 1; m < 32; m <<= 1) mx = fmaxf(mx, __shfl_xor(mx, m));
      const float e = __expf(sc - mx);
      float se = e;
#pragma unroll
      for (int m = 1; m < 32; m <<= 1) se += __shfl_xor(se, m);
      S_out[(size_t)(b0 + p) * 32 + k] = e * __builtin_amdgcn_rcpf(se);
    }
    // No extra barrier: accs reads finished before bar2; cwsn reads (t<128)
    // finish before those threads reach next iteration's bar1, which gates
    // the next cwsn writes.
    __syncthreads();
  }
}

// ---------------------------------------------------------------------------
// Phase 2a: partial pooled. Block = (b, chunk c of 64 points), 128 blocks x
// 256 threads = (k = t&31, fs = t>>5; features [fs*16, fs*16+16)).
// part[b][c][k][f] = sum_{n in chunk} S[b][n][k] * x[b][n][f]
// x is read exactly once across all blocks.
// ---------------------------------------------------------------------------
#define CHUNKS 16
#define CHUNK_N 64

__global__ __launch_bounds__(256) void mempool_pool(
    const float* __restrict__ x, const float* __restrict__ S,
    float* __restrict__ part) {
  const int b = blockIdx.x >> 4;
  const int c = blockIdx.x & 15;
  const int t = threadIdx.x;
  const int k = t & 31;
  const int fs = t >> 5;  // 0..7
  const int n0 = c * CHUNK_N;

  const float4* x4 = reinterpret_cast<const float4*>(x) +
                     ((size_t)b * 1024 + n0) * 32 + fs * 4;
  const float* Sb = S + ((size_t)b * 1024 + n0) * 32 + k;

  float4 a0 = {0, 0, 0, 0}, a1 = {0, 0, 0, 0}, a2 = {0, 0, 0, 0},
         a3 = {0, 0, 0, 0};
#pragma unroll 4
  for (int n = 0; n < CHUNK_N; ++n) {
    const float s = Sb[n * 32];
    const float4 v0 = x4[n * 32 + 0];
    const float4 v1 = x4[n * 32 + 1];
    const float4 v2 = x4[n * 32 + 2];
    const float4 v3 = x4[n * 32 + 3];
    a0.x += s * v0.x; a0.y += s * v0.y; a0.z += s * v0.z; a0.w += s * v0.w;
    a1.x += s * v1.x; a1.y += s * v1.y; a1.z += s * v1.z; a1.w += s * v1.w;
    a2.x += s * v2.x; a2.y += s * v2.y; a2.z += s * v2.z; a2.w += s * v2.w;
    a3.x += s * v3.x; a3.y += s * v3.y; a3.z += s * v3.z; a3.w += s * v3.w;
  }

  float4* p4 = reinterpret_cast<float4*>(part) +
               (((size_t)(b * CHUNKS + c) * 32 + k) * 32 + fs * 4);
  p4[0] = a0;
  p4[1] = a1;
  p4[2] = a2;
  p4[3] = a3;
}

// ---------------------------------------------------------------------------
// Phase 2b: finalize. Block = (b,k), 256 blocks x 128 threads.
// pooled[f] = sum_c part[b][c][k][f]; out[b][k][fo] = leaky(pooled . lin_w[fo])
// ---------------------------------------------------------------------------
__global__ __launch_bounds__(128) void mempool_out(
    const float* __restrict__ part, const float* __restrict__ lin_w,
    float* __restrict__ out) {
  const int b = blockIdx.x >> 5;
  const int k = blockIdx.x & 31;
  const int t = threadIdx.x;  // 0..127

  __shared__ float pooled[128];
  const float* pp = part + (((size_t)b * CHUNKS) * 32 + k) * 128 + t;
  float pf = 0.f;
#pragma unroll
  for (int c = 0; c < CHUNKS; ++c) pf += pp[(size_t)c * 32 * 128];
  pooled[t] = pf;
  __syncthreads();

  const float4* w4 = reinterpret_cast<const float4*>(lin_w) + t * 32;
  const float4* pl4 = reinterpret_cast<const float4*>(pooled);
  float o = 0.f;
#pragma unroll
  for (int j = 0; j < 32; ++j) {
    const float4 w = w4[j];
    const float4 p = pl4[j];
    o += w.x * p.x + w.y * p.y + w.z * p.z + w.w * p.w;
  }
  o = (o >= 0.f) ? o : 0.01f * o;
  out[(size_t)(b * 32 + k) * 128 + t] = o;
}

// ---------------------------------------------------------------------------
// Fallback phase 2 (round-1 style, no workspace): block = (b,k).
// ---------------------------------------------------------------------------
__global__ __launch_bounds__(256) void mempool_phase2_fb(
    const float* __restrict__ x, const float* __restrict__ S,
    const float* __restrict__ lin_w, float* __restrict__ out) {
  const int b = blockIdx.x >> 5;
  const int k = blockIdx.x & 31;
  const int t = threadIdx.x;
  const int fq = t & 31;
  const int seg = t >> 5;

  const float4* xq = reinterpret_cast<const float4*>(x) + (size_t)b * 1024 * 32;
  const float* Sb = S + (size_t)b * 1024 * 32 + k;

  float4 acc = {0.f, 0.f, 0.f, 0.f};
  const int n0 = seg * 128;
#pragma unroll 4
  for (int n = n0; n < n0 + 128; ++n) {
    const float sv = Sb[(size_t)n * 32];
    const float4 xv = xq[n * 32 + fq];
    acc.x += sv * xv.x;
    acc.y += sv * xv.y;
    acc.z += sv * xv.z;
    acc.w += sv * xv.w;
  }

  __shared__ float4 red[8][32];
  red[seg][fq] = acc;
  __syncthreads();

  __shared__ float4 pooled4[32];
  if (t < 32) {
    float4 a = red[0][t];
#pragma unroll
    for (int ss = 1; ss < 8; ++ss) {
      const float4 r = red[ss][t];
      a.x += r.x; a.y += r.y; a.z += r.z; a.w += r.w;
    }
    pooled4[t] = a;
  }
  __syncthreads();

  if (t < 128) {
    const float4* wq = reinterpret_cast<const float4*>(lin_w) + t * 32;
    float o = 0.f;
#pragma unroll
    for (int j = 0; j < 32; ++j) {
      const float4 w = wq[j];
      const float4 p = pooled4[j];
      o += w.x * p.x + w.y * p.y + w.z * p.z + w.w * p.w;
    }
    o = (o >= 0.f) ? o : 0.01f * o;
    out[(size_t)(b * 32 + k) * 128 + t] = o;
  }
}

extern "C" void kernel_launch(void* const* d_in, const int* in_sizes, int n_in,
                              void* d_out, int out_size, void* d_ws, size_t ws_size,
                              hipStream_t stream) {
  const float* x = (const float*)d_in[0];       // [8,1024,128]
  const float* keys = (const float*)d_in[1];    // [4,32,128]
  const float* conv_w = (const float*)d_in[2];  // [4]
  const float* lin_w = (const float*)d_in[3];   // [128,128]

  float* out = (float*)d_out;            // [8,32,128]
  float* S_out = (float*)d_out + 32768;  // [8,1024,32]

  mempool_phase1<<<8192 / P1_PPB, 512, 0, stream>>>(x, keys, conv_w, S_out);

  const size_t part_bytes = (size_t)8 * CHUNKS * 32 * 128 * sizeof(float);  // 2 MB
  if (ws_size >= part_bytes) {
    float* part = (float*)d_ws;
    mempool_pool<<<8 * CHUNKS, 256, 0, stream>>>(x, S_out, part);
    mempool_out<<<8 * 32, 128, 0, stream>>>(part, lin_w, out);
  } else {
    mempool_phase2_fb<<<8 * 32, 256, 0, stream>>>(x, S_out, lin_w, out);
  }
}

// Round 4
// 43.192 us; speedup vs baseline: 1.6207x; 1.6207x over previous
//
#include <hip/hip_runtime.h>

// Problem constants: B=8, N=1024, F=128, H=4, K=32, TAU=1

// ---------------------------------------------------------------------------
// Prep: transpose keys into KTQ[fq][hk] (float4 = K[hk][4fq..4fq+3]).
// 4096 float4s; scattered reads, coalesced writes. Runs once, 64 KB.
// ---------------------------------------------------------------------------
__global__ __launch_bounds__(256) void mempool_prep(
    const float* __restrict__ keys, float* __restrict__ ktq) {
  const int i = blockIdx.x * 256 + threadIdx.x;  // 0..4095
  const int fq = i >> 7;
  const int hk = i & 127;
  reinterpret_cast<float4*>(ktq)[i] =
      reinterpret_cast<const float4*>(keys)[hk * 32 + fq];
}

// ---------------------------------------------------------------------------
// Phase 1: S[bn][k] for all 8192 points.
// 512 blocks x 256 threads; thread = (hk = t&127, half = t>>7), 8 points each.
// KTQ staged into LDS (64 KB, linear). Main loop: 32 f-quads, each:
//   1 ds_read_b128 (key frag, conflict-free) + 8 broadcast global x loads
//   + 64 VALU. No barriers until the epilogue.
// Epilogue: Student-t + per-head (32-lane shfl) normalize -> cwsn LDS ->
// barrier -> conv-combine + softmax over k (32-lane shfl) -> S_out.
// Per-thread regs: acc[8] + kq[4] + in-flight x -> ~55 VGPRs (no big arrays).
// ---------------------------------------------------------------------------
__global__ __launch_bounds__(256) void mempool_phase1(
    const float* __restrict__ x, const float* __restrict__ ktq,
    const float* __restrict__ conv_w, float* __restrict__ S_out) {
  const int t = threadIdx.x;
  const int hk = t & 127;
  const int half = t >> 7;

  __shared__ float4 kt[4096];            // KTQ[fq*128 + hk], 64 KB
  __shared__ float cwsn[16][4][32];      // 8 KB

  // Stage KTQ linearly: 16 float4 per thread, coalesced read + write.
  {
    const float4* g = reinterpret_cast<const float4*>(ktq);
#pragma unroll
    for (int i = 0; i < 16; ++i) kt[t + i * 256] = g[t + i * 256];
  }
  __syncthreads();

  const int bn0 = blockIdx.x * 16 + half * 8;  // first of this thread's 8 pts
  const float4* x4 = reinterpret_cast<const float4*>(x) + (size_t)bn0 * 32;

  float acc[8];
#pragma unroll
  for (int p = 0; p < 8; ++p) acc[p] = 0.f;

  for (int fq = 0; fq < 32; ++fq) {
    const float4 kq = kt[fq * 128 + hk];
#pragma unroll
    for (int p = 0; p < 8; ++p) {
      const float4 xv = x4[p * 32 + fq];  // wave-uniform addr -> broadcast
      acc[p] += fabsf(kq.x - xv.x) + fabsf(kq.y - xv.y) +
                fabsf(kq.z - xv.z) + fabsf(kq.w - xv.w);
    }
  }

  // Student-t + per-head normalize (32-lane groups share head h = hk>>5).
  const float cw = conv_w[hk >> 5];
#pragma unroll
  for (int p = 0; p < 8; ++p) {
    const float d = acc[p];
    const float tv = __builtin_amdgcn_rcpf(1.f + d * d);
    float hs = tv;
#pragma unroll
    for (int m = 1; m < 32; m <<= 1) hs += __shfl_xor(hs, m);
    cwsn[half * 8 + p][hk >> 5][hk & 31] = cw * tv * __builtin_amdgcn_rcpf(hs);
  }
  __syncthreads();

  // Conv-combine over heads + softmax over k. 256 thr x 2 passes = 16 pts.
#pragma unroll
  for (int pp = 0; pp < 2; ++pp) {
    const int p = pp * 8 + (t >> 5);
    const int k = t & 31;
    float sc = cwsn[p][0][k] + cwsn[p][1][k] + cwsn[p][2][k] + cwsn[p][3][k];
    float mx = sc;
#pragma unroll
    for (int m = 1; m < 32; m <<= 1) mx = fmaxf(mx, __shfl_xor(mx, m));
    const float e = __expf(sc - mx);
    float se = e;
#pragma unroll
    for (int m = 1; m < 32; m <<= 1) se += __shfl_xor(se, m);
    S_out[(size_t)(blockIdx.x * 16 + p) * 32 + k] =
        e * __builtin_amdgcn_rcpf(se);
  }
}

// ---------------------------------------------------------------------------
// Phase 2a: partial pooled. Block = (b, chunk c of 64 points); 256 threads =
// (k = t&31, fs = t>>5). x addresses independent of k -> broadcast; x is read
// exactly once across all blocks.
// ---------------------------------------------------------------------------
#define CHUNKS 16
#define CHUNK_N 64

__global__ __launch_bounds__(256) void mempool_pool(
    const float* __restrict__ x, const float* __restrict__ S,
    float* __restrict__ part) {
  const int b = blockIdx.x >> 4;
  const int c = blockIdx.x & 15;
  const int t = threadIdx.x;
  const int k = t & 31;
  const int fs = t >> 5;  // 0..7
  const int n0 = c * CHUNK_N;

  const float4* x4 = reinterpret_cast<const float4*>(x) +
                     ((size_t)b * 1024 + n0) * 32 + fs * 4;
  const float* Sb = S + ((size_t)b * 1024 + n0) * 32 + k;

  float4 a0 = {0, 0, 0, 0}, a1 = {0, 0, 0, 0}, a2 = {0, 0, 0, 0},
         a3 = {0, 0, 0, 0};
#pragma unroll 4
  for (int n = 0; n < CHUNK_N; ++n) {
    const float s = Sb[n * 32];
    const float4 v0 = x4[n * 32 + 0];
    const float4 v1 = x4[n * 32 + 1];
    const float4 v2 = x4[n * 32 + 2];
    const float4 v3 = x4[n * 32 + 3];
    a0.x += s * v0.x; a0.y += s * v0.y; a0.z += s * v0.z; a0.w += s * v0.w;
    a1.x += s * v1.x; a1.y += s * v1.y; a1.z += s * v1.z; a1.w += s * v1.w;
    a2.x += s * v2.x; a2.y += s * v2.y; a2.z += s * v2.z; a2.w += s * v2.w;
    a3.x += s * v3.x; a3.y += s * v3.y; a3.z += s * v3.z; a3.w += s * v3.w;
  }

  float4* p4 = reinterpret_cast<float4*>(part) +
               (((size_t)(b * CHUNKS + c) * 32 + k) * 32 + fs * 4);
  p4[0] = a0;
  p4[1] = a1;
  p4[2] = a2;
  p4[3] = a3;
}

// ---------------------------------------------------------------------------
// Phase 2b: finalize. Block = (b,k), 128 threads.
// ---------------------------------------------------------------------------
__global__ __launch_bounds__(128) void mempool_out(
    const float* __restrict__ part, const float* __restrict__ lin_w,
    float* __restrict__ out) {
  const int b = blockIdx.x >> 5;
  const int k = blockIdx.x & 31;
  const int t = threadIdx.x;  // 0..127

  __shared__ float pooled[128];
  const float* pp = part + (((size_t)b * CHUNKS) * 32 + k) * 128 + t;
  float pf = 0.f;
#pragma unroll
  for (int c = 0; c < CHUNKS; ++c) pf += pp[(size_t)c * 32 * 128];
  pooled[t] = pf;
  __syncthreads();

  const float4* w4 = reinterpret_cast<const float4*>(lin_w) + t * 32;
  const float4* pl4 = reinterpret_cast<const float4*>(pooled);
  float o = 0.f;
#pragma unroll
  for (int j = 0; j < 32; ++j) {
    const float4 w = w4[j];
    const float4 p = pl4[j];
    o += w.x * p.x + w.y * p.y + w.z * p.z + w.w * p.w;
  }
  o = (o >= 0.f) ? o : 0.01f * o;
  out[(size_t)(b * 32 + k) * 128 + t] = o;
}

// ---------------------------------------------------------------------------
// Fallbacks (no workspace): round-1 structure.
// ---------------------------------------------------------------------------
__global__ __launch_bounds__(256) void mempool_phase1_fb(
    const float* __restrict__ x, const float* __restrict__ keys,
    const float* __restrict__ conv_w, float* __restrict__ S_out) {
  const int t = threadIdx.x;
  const int hk = t & 127;
  const int half = t >> 7;

  const float4* kq = reinterpret_cast<const float4*>(keys) + hk * 32 + half * 16;
  const float cw = conv_w[(t >> 5) & 3];

  __shared__ float lds_half[128];
  __shared__ float lds_ws[128];

  const int base = blockIdx.x * 8;
  for (int p = 0; p < 8; ++p) {
    const int bn = base + p;
    const float4* xq = reinterpret_cast<const float4*>(x) + bn * 32 + half * 16;
    float a0 = 0.f;
#pragma unroll
    for (int j = 0; j < 16; ++j) {
      const float4 kv = kq[j];
      const float4 xv = xq[j];
      a0 += fabsf(kv.x - xv.x) + fabsf(kv.y - xv.y) + fabsf(kv.z - xv.z) +
            fabsf(kv.w - xv.w);
    }
    if (t >= 128) lds_half[hk] = a0;
    __syncthreads();
    if (t < 128) {
      const float d = a0 + lds_half[hk];
      const float tv = 1.0f / (1.0f + d * d);
      float hs = tv;
#pragma unroll
      for (int m = 1; m < 32; m <<= 1) hs += __shfl_xor(hs, m);
      lds_ws[hk] = cw * tv / hs;
    }
    __syncthreads();
    if (t < 32) {
      float sc = lds_ws[t] + lds_ws[32 + t] + lds_ws[64 + t] + lds_ws[96 + t];
      float mx = sc;
#pragma unroll
      for (int m = 1; m < 32; m <<= 1) mx = fmaxf(mx, __shfl_xor(mx, m));
      const float e = __expf(sc - mx);
      float se = e;
#pragma unroll
      for (int m = 1; m < 32; m <<= 1) se += __shfl_xor(se, m);
      S_out[bn * 32 + t] = e / se;
    }
    __syncthreads();
  }
}

__global__ __launch_bounds__(256) void mempool_phase2_fb(
    const float* __restrict__ x, const float* __restrict__ S,
    const float* __restrict__ lin_w, float* __restrict__ out) {
  const int b = blockIdx.x >> 5;
  const int k = blockIdx.x & 31;
  const int t = threadIdx.x;
  const int fq = t & 31;
  const int seg = t >> 5;

  const float4* xq = reinterpret_cast<const float4*>(x) + (size_t)b * 1024 * 32;
  const float* Sb = S + (size_t)b * 1024 * 32 + k;

  float4 acc = {0.f, 0.f, 0.f, 0.f};
  const int n0 = seg * 128;
#pragma unroll 4
  for (int n = n0; n < n0 + 128; ++n) {
    const float sv = Sb[(size_t)n * 32];
    const float4 xv = xq[n * 32 + fq];
    acc.x += sv * xv.x;
    acc.y += sv * xv.y;
    acc.z += sv * xv.z;
    acc.w += sv * xv.w;
  }

  __shared__ float4 red[8][32];
  red[seg][fq] = acc;
  __syncthreads();

  __shared__ float4 pooled4[32];
  if (t < 32) {
    float4 a = red[0][t];
#pragma unroll
    for (int ss = 1; ss < 8; ++ss) {
      const float4 r = red[ss][t];
      a.x += r.x; a.y += r.y; a.z += r.z; a.w += r.w;
    }
    pooled4[t] = a;
  }
  __syncthreads();

  if (t < 128) {
    const float4* wq = reinterpret_cast<const float4*>(lin_w) + t * 32;
    float o = 0.f;
#pragma unroll
    for (int j = 0; j < 32; ++j) {
      const float4 w = wq[j];
      const float4 p = pooled4[j];
      o += w.x * p.x + w.y * p.y + w.z * p.z + w.w * p.w;
    }
    o = (o >= 0.f) ? o : 0.01f * o;
    out[(size_t)(b * 32 + k) * 128 + t] = o;
  }
}

extern "C" void kernel_launch(void* const* d_in, const int* in_sizes, int n_in,
                              void* d_out, int out_size, void* d_ws, size_t ws_size,
                              hipStream_t stream) {
  const float* x = (const float*)d_in[0];       // [8,1024,128]
  const float* keys = (const float*)d_in[1];    // [4,32,128]
  const float* conv_w = (const float*)d_in[2];  // [4]
  const float* lin_w = (const float*)d_in[3];   // [128,128]

  float* out = (float*)d_out;            // [8,32,128]
  float* S_out = (float*)d_out + 32768;  // [8,1024,32]

  const size_t ktq_floats = 128 * 128;                           // 64 KB
  const size_t part_floats = (size_t)8 * CHUNKS * 32 * 128;      // 2 MB
  const size_t need = (ktq_floats + part_floats) * sizeof(float);

  if (ws_size >= need) {
    float* ktq = (float*)d_ws;
    float* part = (float*)d_ws + ktq_floats;
    mempool_prep<<<16, 256, 0, stream>>>(keys, ktq);
    mempool_phase1<<<512, 256, 0, stream>>>(x, ktq, conv_w, S_out);
    mempool_pool<<<8 * CHUNKS, 256, 0, stream>>>(x, S_out, part);
    mempool_out<<<8 * 32, 128, 0, stream>>>(part, lin_w, out);
  } else {
    mempool_phase1_fb<<<1024, 256, 0, stream>>>(x, keys, conv_w, S_out);
    mempool_phase2_fb<<<8 * 32, 256, 0, stream>>>(x, S_out, lin_w, out);
  }
}